// Round 5
// baseline (867.004 us; speedup 1.0000x reference)
//
#include <hip/hip_runtime.h>
#include <math.h>

#define N_NODES 100000
#define N_EDGES 1600000
#define F_IN 512
#define HD 64                    // H*D = 8*8
#define CC 7
#define NB ((N_NODES + 1023) / 1024)   // 98 scan blocks
#define NKT (F_IN / 32)                // 16 K-steps for MFMA GEMM1
#define NBUCK ((N_NODES + 255) / 256)  // 391 dst buckets (256 nodes each)

typedef __attribute__((ext_vector_type(8))) short short8;
typedef __attribute__((ext_vector_type(4))) float f32x4;

// float -> bf16 bits, round-to-nearest-even
__device__ inline unsigned short f2bf(float f) {
    union { float f; unsigned u; } v; v.f = f;
    unsigned u = v.u;
    return (unsigned short)((u + 0x7fffu + ((u >> 16) & 1u)) >> 16);
}
__device__ inline float bf2f(unsigned short b) {
    union { unsigned u; float f; } v; v.u = ((unsigned)b) << 16;
    return v.f;
}

// ---- W1 -> bf16 in exact B-fragment order: wf[kt][ct][lane][8] ----
__global__ void w1prep_kernel(const float* __restrict__ W1,
                              unsigned short* __restrict__ wf) {
    int t = blockIdx.x * 256 + threadIdx.x;       // [0, NKT*4*64)
    if (t >= NKT * 4 * 64) return;
    int lane = t & 63;
    int ct = (t >> 6) & 3;
    int kt = t >> 8;
    int k0 = kt * 32 + (lane >> 4) * 8;
    int col = ct * 16 + (lane & 15);
    unsigned short* dst = wf + (size_t)t * 8;
    #pragma unroll
    for (int j = 0; j < 8; ++j) dst[j] = f2bf(W1[(k0 + j) * HD + col]);
}

// ------------ GEMM1 (MFMA, no LDS): h1b[N,64](bf16) = x @ W1 --------------
__global__ __launch_bounds__(256) void gemm1_kernel(const float* __restrict__ x,
                                                    const unsigned short* __restrict__ wf,
                                                    unsigned short* __restrict__ h1b) {
    const int wave = threadIdx.x >> 6;
    const int lane = threadIdx.x & 63;
    int arow = blockIdx.x * 64 + wave * 16 + (lane & 15);
    if (arow >= N_NODES) arow = N_NODES - 1;       // clamp for load only
    const float* xp = x + (size_t)arow * F_IN + (lane >> 4) * 8;
    const short8* wp = (const short8*)wf;

    f32x4 acc[4] = {};
    #pragma unroll 4
    for (int kt = 0; kt < NKT; ++kt) {
        f32x4 a0 = *(const f32x4*)(xp + kt * 32);
        f32x4 a1 = *(const f32x4*)(xp + kt * 32 + 4);
        union { short8 s; unsigned short u[8]; } af;
        af.u[0] = f2bf(a0.x); af.u[1] = f2bf(a0.y);
        af.u[2] = f2bf(a0.z); af.u[3] = f2bf(a0.w);
        af.u[4] = f2bf(a1.x); af.u[5] = f2bf(a1.y);
        af.u[6] = f2bf(a1.z); af.u[7] = f2bf(a1.w);
        #pragma unroll
        for (int ct = 0; ct < 4; ++ct) {
            short8 bf = wp[kt * 256 + ct * 64 + lane];
            acc[ct] = __builtin_amdgcn_mfma_f32_16x16x32_bf16(af.s, bf, acc[ct], 0, 0, 0);
        }
    }
    // C/D layout: col = lane&15, row = (lane>>4)*4 + r
    const int orow_base = blockIdx.x * 64 + wave * 16 + (lane >> 4) * 4;
    const int ocol = lane & 15;
    #pragma unroll
    for (int ct = 0; ct < 4; ++ct) {
        #pragma unroll
        for (int r = 0; r < 4; ++r) {
            int orow = orow_base + r;
            if (orow < N_NODES)
                h1b[(size_t)orow * HD + ct * 16 + ocol] = f2bf(acc[ct][r]);
        }
    }
}

// ------------- per-node attention halves, layer 1: [N,8] each -------------
__global__ void att1_kernel(const unsigned short* __restrict__ h1b,
                            const float* __restrict__ a1s, const float* __restrict__ a1d,
                            float* __restrict__ als, float* __restrict__ ald) {
    int tid = blockIdx.x * blockDim.x + threadIdx.x;
    if (tid >= N_NODES * 8) return;
    int n = tid >> 3, h = tid & 7;
    const unsigned short* hp = h1b + (size_t)n * HD + h * 8;
    const float* as = a1s + h * 8;
    const float* ad = a1d + h * 8;
    float s = 0.f, d = 0.f;
    #pragma unroll
    for (int k = 0; k < 8; ++k) { float v = bf2f(hp[k]); s += v * as[k]; d += v * ad[k]; }
    als[tid] = s; ald[tid] = d;
}

// ----------------------- CSR build: histogram ------------------------------
__global__ void hist_kernel(const int* __restrict__ ei, int* __restrict__ deg) {
    int i = blockIdx.x * blockDim.x + threadIdx.x;
    if (i >= N_EDGES) return;
    atomicAdd(&deg[ei[N_EDGES + i]], 1);
}

// ------- hierarchical scan stage 1: per-block exclusive prefix + bsum ------
__global__ __launch_bounds__(1024) void scan1_kernel(const int* __restrict__ deg,
                                                     int* __restrict__ lp,
                                                     int* __restrict__ bsum) {
    __shared__ int wsum[16];
    const int t = threadIdx.x;
    const int idx = blockIdx.x * 1024 + t;
    const int lane = t & 63, w = t >> 6;
    int d = (idx < N_NODES) ? deg[idx] : 0;
    int x = d;
    #pragma unroll
    for (int o = 1; o < 64; o <<= 1) {
        int v = __shfl_up(x, o, 64);
        if (lane >= o) x += v;
    }
    if (lane == 63) wsum[w] = x;
    __syncthreads();
    if (w == 0) {
        int s = (lane < 16) ? wsum[lane] : 0;
        #pragma unroll
        for (int o = 1; o < 16; o <<= 1) {
            int v = __shfl_up(s, o, 64);
            if (lane >= o) s += v;
        }
        if (lane < 16) wsum[lane] = s;
    }
    __syncthreads();
    int woff = (w > 0) ? wsum[w - 1] : 0;
    if (idx < N_NODES) lp[idx] = x - d + woff;         // exclusive within block
    if (t == 1023) bsum[blockIdx.x] = woff + x;        // block total
}

// ----- scan stage 2: one small block scans the 98 block sums ----------------
__global__ __launch_bounds__(128) void scan2_kernel(const int* __restrict__ bsum,
                                                    int* __restrict__ boff,
                                                    int* __restrict__ rowptr) {
    __shared__ int wt[2];
    const int t = threadIdx.x;
    const int lane = t & 63, w = t >> 6;
    int v = (t < NB) ? bsum[t] : 0;
    int x = v;
    #pragma unroll
    for (int o = 1; o < 64; o <<= 1) {
        int u = __shfl_up(x, o, 64);
        if (lane >= o) x += u;
    }
    if (lane == 63) wt[w] = x;
    __syncthreads();
    int off = (w == 1) ? wt[0] : 0;
    int ex = x - v + off;
    if (t < NB) boff[t] = ex;
    if (t == NB - 1) rowptr[N_NODES] = ex + v;
}

// ---- scan stage 3: add block offsets; write rowptr, cursor, bucket cursors ----
__global__ __launch_bounds__(1024) void scan3_kernel(const int* __restrict__ lp,
                                                     const int* __restrict__ boff,
                                                     int* __restrict__ rowptr,
                                                     int* __restrict__ cursor,
                                                     int* __restrict__ bcur) {
    int idx = blockIdx.x * 1024 + threadIdx.x;
    if (idx >= N_NODES) return;
    int r = lp[idx] + boff[blockIdx.x];
    rowptr[idx] = r;
    cursor[idx] = r;
    if ((idx & 255) == 0) bcur[idx >> 8] = r;          // bucket base = rowptr[b*256]
}

// --- CSR pass A: bin edges into per-bucket regions (sequential writes) -----
__global__ void binscatter_kernel(const int* __restrict__ ei, int* __restrict__ bcur,
                                  int2* __restrict__ pairs) {
    int i = blockIdx.x * blockDim.x + threadIdx.x;
    if (i >= N_EDGES) return;
    int s = ei[i];
    int t = ei[N_EDGES + i];
    int pos = atomicAdd(&bcur[t >> 8], 1);
    pairs[pos] = make_int2(s, t);
}

// --- CSR pass B: finalize within each bucket (L2-resident write window) ----
__global__ __launch_bounds__(256) void finalize_kernel(const int* __restrict__ rowptr,
                                                       const int2* __restrict__ pairs,
                                                       int* __restrict__ cursor,
                                                       int* __restrict__ csr_src) {
    int b = blockIdx.x;
    int n0 = b << 8;
    int n1 = n0 + 256; if (n1 > N_NODES) n1 = N_NODES;
    int rs = rowptr[n0], re = rowptr[n1];
    for (int j = rs + threadIdx.x; j < re; j += 256) {
        int2 p = pairs[j];
        int pos = atomicAdd(&cursor[p.y], 1);
        csr_src[pos] = p.x;
    }
}

// ---- gather layer 1: per-dst wave; fused ELU + GEMM2(64->7) + att2 halves ----
__global__ __launch_bounds__(256) void gather1_kernel(
        const int* __restrict__ rowptr, const int* __restrict__ csr_src,
        const float* __restrict__ als, const float* __restrict__ ald,
        const unsigned short* __restrict__ h1b, const float* __restrict__ b1,
        const float* __restrict__ W2, const float* __restrict__ a2s,
        const float* __restrict__ a2d,
        unsigned short* __restrict__ g2b, float* __restrict__ al2s,
        float* __restrict__ al2d) {
    int wid = (blockIdx.x * 256 + threadIdx.x) >> 6;     // one wave per dst node
    if (wid >= N_NODES) return;
    const int lane = threadIdx.x & 63;
    const int h = lane >> 3;
    const int rs = rowptr[wid], re = rowptr[wid + 1];
    const float aldt = ald[wid * 8 + h];
    // self loop
    float e = als[wid * 8 + h] + aldt;
    e = (e >= 0.f) ? e : 0.2f * e;
    float p = __expf(e);
    float acc = p * bf2f(h1b[(size_t)wid * HD + lane]);
    float z = p;
    // incoming edges, with next-src prefetch
    int j = rs;
    int s_next = (j < re) ? csr_src[j] : 0;
    while (j < re) {
        int s = s_next;
        ++j;
        if (j < re) s_next = csr_src[j];
        float e2 = als[s * 8 + h] + aldt;
        e2 = (e2 >= 0.f) ? e2 : 0.2f * e2;
        float p2 = __expf(e2);
        acc = fmaf(p2, bf2f(h1b[(size_t)s * HD + lane]), acc);
        z += p2;
    }
    // epilogue: alpha-normalize + bias + ELU
    float v = acc / z + b1[lane];
    v = (v > 0.f) ? v : (__expf(v) - 1.f);
    // fused GEMM2: g[c] = sum_j v_j * W2[j][c]  (butterfly over the wave)
    float w[CC];
    #pragma unroll
    for (int c = 0; c < CC; ++c) w[c] = W2[lane * CC + c];
    float g[CC];
    #pragma unroll
    for (int c = 0; c < CC; ++c) {
        float r = v * w[c];
        #pragma unroll
        for (int d = 1; d < 64; d <<= 1) r += __shfl_xor(r, d, 64);
        g[c] = r;
    }
    float s2 = 0.f, d2 = 0.f;
    #pragma unroll
    for (int c = 0; c < CC; ++c) { s2 += g[c] * a2s[c]; d2 += g[c] * a2d[c]; }
    if (lane < CC) g2b[(size_t)wid * 8 + lane] = f2bf(g[lane]);
    if (lane == CC) g2b[(size_t)wid * 8 + CC] = 0;
    if (lane == 8) al2s[wid] = s2;
    if (lane == 9) al2d[wid] = d2;
}

// -------- gather layer 2: 8 lanes per dst node, fused log_softmax ----------
__global__ __launch_bounds__(256) void gather2_kernel(
        const int* __restrict__ rowptr, const int* __restrict__ csr_src,
        const float* __restrict__ al2s, const float* __restrict__ al2d,
        const unsigned short* __restrict__ g2b, const float* __restrict__ b2,
        float* __restrict__ out) {
    int gid = blockIdx.x * 256 + threadIdx.x;
    int n = gid >> 3, c = gid & 7;
    if (n >= N_NODES) return;
    const int rs = rowptr[n], re = rowptr[n + 1];
    const float adn = al2d[n];
    float e = al2s[n] + adn;
    e = (e >= 0.f) ? e : 0.2f * e;
    float p = __expf(e);
    float acc = p * bf2f(g2b[(size_t)n * 8 + c]);
    float z = p;
    int j = rs;
    int s_next = (j < re) ? csr_src[j] : 0;
    while (j < re) {
        int s = s_next;
        ++j;
        if (j < re) s_next = csr_src[j];
        float e2 = al2s[s] + adn;
        e2 = (e2 >= 0.f) ? e2 : 0.2f * e2;
        float p2 = __expf(e2);
        acc = fmaf(p2, bf2f(g2b[(size_t)s * 8 + c]), acc);
        z += p2;
    }
    float o = (c < CC) ? (acc / z + b2[c]) : -1e30f;
    float m = o;
    #pragma unroll
    for (int d = 1; d < 8; d <<= 1) m = fmaxf(m, __shfl_xor(m, d, 8));
    float ex = (c < CC) ? __expf(o - m) : 0.f;
    float sum = ex;
    #pragma unroll
    for (int d = 1; d < 8; d <<= 1) sum += __shfl_xor(sum, d, 8);
    float lse = m + __logf(sum);
    if (c < CC) out[(size_t)n * CC + c] = o - lse;
}

extern "C" void kernel_launch(void* const* d_in, const int* in_sizes, int n_in,
                              void* d_out, int out_size, void* d_ws, size_t ws_size,
                              hipStream_t stream) {
    const float* x   = (const float*)d_in[0];
    const int*   ei  = (const int*)d_in[1];
    const float* W1  = (const float*)d_in[2];
    const float* a1s = (const float*)d_in[3];
    const float* a1d = (const float*)d_in[4];
    const float* b1  = (const float*)d_in[5];
    const float* W2  = (const float*)d_in[6];
    const float* a2s = (const float*)d_in[7];
    const float* a2d = (const float*)d_in[8];
    const float* b2  = (const float*)d_in[9];
    float* out = (float*)d_out;

    // byte-offset workspace allocator (64B aligned)
    char* base = (char*)d_ws;
    size_t off = 0;
    auto alloc = [&](size_t bytes) { char* p = base + off; off = (off + bytes + 63) & ~(size_t)63; return p; };
    unsigned short* h1b = (unsigned short*)alloc((size_t)N_NODES * HD * 2);
    unsigned short* wf  = (unsigned short*)alloc((size_t)NKT * 4 * 64 * 8 * 2);
    float* als  = (float*)alloc((size_t)N_NODES * 8 * 4);
    float* ald  = (float*)alloc((size_t)N_NODES * 8 * 4);
    unsigned short* g2b = (unsigned short*)alloc((size_t)N_NODES * 8 * 2);
    float* al2s = (float*)alloc((size_t)N_NODES * 4);
    float* al2d = (float*)alloc((size_t)N_NODES * 4);
    int* rowptr = (int*)alloc((size_t)(N_NODES + 1) * 4);
    int* cursor = (int*)alloc((size_t)N_NODES * 4);
    int* deg    = (int*)alloc((size_t)N_NODES * 4);
    int* lp     = (int*)alloc((size_t)N_NODES * 4);
    int* bsum   = (int*)alloc((size_t)NB * 4);
    int* boff   = (int*)alloc((size_t)NB * 4);
    int* bcur   = (int*)alloc((size_t)NBUCK * 4);
    int2* pairs = (int2*)alloc((size_t)N_EDGES * 8);
    int* csr_src= (int*)alloc((size_t)N_EDGES * 4);

    hipMemsetAsync(deg, 0, (size_t)N_NODES * sizeof(int), stream);
    w1prep_kernel<<<(NKT * 4 * 64 + 255) / 256, 256, 0, stream>>>(W1, wf);
    hist_kernel<<<(N_EDGES + 255) / 256, 256, 0, stream>>>(ei, deg);
    scan1_kernel<<<NB, 1024, 0, stream>>>(deg, lp, bsum);
    scan2_kernel<<<1, 128, 0, stream>>>(bsum, boff, rowptr);
    scan3_kernel<<<NB, 1024, 0, stream>>>(lp, boff, rowptr, cursor, bcur);
    binscatter_kernel<<<(N_EDGES + 255) / 256, 256, 0, stream>>>(ei, bcur, pairs);

    gemm1_kernel<<<(N_NODES + 63) / 64, 256, 0, stream>>>(x, wf, h1b);
    att1_kernel<<<(N_NODES * 8 + 255) / 256, 256, 0, stream>>>(h1b, a1s, a1d, als, ald);

    finalize_kernel<<<NBUCK, 256, 0, stream>>>(rowptr, pairs, cursor, csr_src);

    gather1_kernel<<<(N_NODES * 64 + 255) / 256, 256, 0, stream>>>(
        rowptr, csr_src, als, ald, h1b, b1, W2, a2s, a2d, g2b, al2s, al2d);
    gather2_kernel<<<(N_NODES * 8 + 255) / 256, 256, 0, stream>>>(
        rowptr, csr_src, al2s, al2d, g2b, b2, out);
}

// Round 6
// 331.016 us; speedup vs baseline: 2.6192x; 2.6192x over previous
//
#include <hip/hip_runtime.h>
#include <math.h>

#define N_NODES 100000
#define N_EDGES 1600000
#define F_IN 512
#define HD 64                    // H*D = 8*8
#define CC 7
#define NB ((N_NODES + 1023) / 1024)   // 98 scan blocks
#define NKT (F_IN / 32)                // 16 K-steps for MFMA GEMM1
#define NBUCK ((N_NODES + 255) / 256)  // 391 dst buckets (256 nodes each)
#define SCHUNK 4096                    // edges per binscatter block
#define SBLK ((N_EDGES + SCHUNK - 1) / SCHUNK)   // 391 blocks

typedef __attribute__((ext_vector_type(8))) short short8;
typedef __attribute__((ext_vector_type(4))) float f32x4;

// float -> bf16 bits, round-to-nearest-even
__device__ inline unsigned short f2bf(float f) {
    union { float f; unsigned u; } v; v.f = f;
    unsigned u = v.u;
    return (unsigned short)((u + 0x7fffu + ((u >> 16) & 1u)) >> 16);
}
__device__ inline float bf2f(unsigned short b) {
    union { unsigned u; float f; } v; v.u = ((unsigned)b) << 16;
    return v.f;
}

// ---- W1 -> bf16 in exact B-fragment order: wf[kt][ct][lane][8] ----
__global__ void w1prep_kernel(const float* __restrict__ W1,
                              unsigned short* __restrict__ wf) {
    int t = blockIdx.x * 256 + threadIdx.x;       // [0, NKT*4*64)
    if (t >= NKT * 4 * 64) return;
    int lane = t & 63;
    int ct = (t >> 6) & 3;
    int kt = t >> 8;
    int k0 = kt * 32 + (lane >> 4) * 8;
    int col = ct * 16 + (lane & 15);
    unsigned short* dst = wf + (size_t)t * 8;
    #pragma unroll
    for (int j = 0; j < 8; ++j) dst[j] = f2bf(W1[(k0 + j) * HD + col]);
}

// ------------ GEMM1 (MFMA, no LDS): h1b[N,64](bf16) = x @ W1 --------------
__global__ __launch_bounds__(256) void gemm1_kernel(const float* __restrict__ x,
                                                    const unsigned short* __restrict__ wf,
                                                    unsigned short* __restrict__ h1b) {
    const int wave = threadIdx.x >> 6;
    const int lane = threadIdx.x & 63;
    int arow = blockIdx.x * 64 + wave * 16 + (lane & 15);
    if (arow >= N_NODES) arow = N_NODES - 1;       // clamp for load only
    const float* xp = x + (size_t)arow * F_IN + (lane >> 4) * 8;
    const short8* wp = (const short8*)wf;

    f32x4 acc[4] = {};
    #pragma unroll 4
    for (int kt = 0; kt < NKT; ++kt) {
        f32x4 a0 = *(const f32x4*)(xp + kt * 32);
        f32x4 a1 = *(const f32x4*)(xp + kt * 32 + 4);
        union { short8 s; unsigned short u[8]; } af;
        af.u[0] = f2bf(a0.x); af.u[1] = f2bf(a0.y);
        af.u[2] = f2bf(a0.z); af.u[3] = f2bf(a0.w);
        af.u[4] = f2bf(a1.x); af.u[5] = f2bf(a1.y);
        af.u[6] = f2bf(a1.z); af.u[7] = f2bf(a1.w);
        #pragma unroll
        for (int ct = 0; ct < 4; ++ct) {
            short8 bf = wp[kt * 256 + ct * 64 + lane];
            acc[ct] = __builtin_amdgcn_mfma_f32_16x16x32_bf16(af.s, bf, acc[ct], 0, 0, 0);
        }
    }
    // C/D layout: col = lane&15, row = (lane>>4)*4 + r
    const int orow_base = blockIdx.x * 64 + wave * 16 + (lane >> 4) * 4;
    const int ocol = lane & 15;
    #pragma unroll
    for (int ct = 0; ct < 4; ++ct) {
        #pragma unroll
        for (int r = 0; r < 4; ++r) {
            int orow = orow_base + r;
            if (orow < N_NODES)
                h1b[(size_t)orow * HD + ct * 16 + ocol] = f2bf(acc[ct][r]);
        }
    }
}

// ------------- per-node attention halves, layer 1: [N,8] each -------------
__global__ void att1_kernel(const unsigned short* __restrict__ h1b,
                            const float* __restrict__ a1s, const float* __restrict__ a1d,
                            float* __restrict__ als, float* __restrict__ ald) {
    int tid = blockIdx.x * blockDim.x + threadIdx.x;
    if (tid >= N_NODES * 8) return;
    int n = tid >> 3, h = tid & 7;
    const unsigned short* hp = h1b + (size_t)n * HD + h * 8;
    const float* as = a1s + h * 8;
    const float* ad = a1d + h * 8;
    float s = 0.f, d = 0.f;
    #pragma unroll
    for (int k = 0; k < 8; ++k) { float v = bf2f(hp[k]); s += v * as[k]; d += v * ad[k]; }
    als[tid] = s; ald[tid] = d;
}

// ----------------------- CSR build: histogram ------------------------------
__global__ void hist_kernel(const int* __restrict__ ei, int* __restrict__ deg) {
    int i = blockIdx.x * blockDim.x + threadIdx.x;
    if (i >= N_EDGES) return;
    atomicAdd(&deg[ei[N_EDGES + i]], 1);
}

// ------- hierarchical scan stage 1: per-block exclusive prefix + bsum ------
__global__ __launch_bounds__(1024) void scan1_kernel(const int* __restrict__ deg,
                                                     int* __restrict__ lp,
                                                     int* __restrict__ bsum) {
    __shared__ int wsum[16];
    const int t = threadIdx.x;
    const int idx = blockIdx.x * 1024 + t;
    const int lane = t & 63, w = t >> 6;
    int d = (idx < N_NODES) ? deg[idx] : 0;
    int x = d;
    #pragma unroll
    for (int o = 1; o < 64; o <<= 1) {
        int v = __shfl_up(x, o, 64);
        if (lane >= o) x += v;
    }
    if (lane == 63) wsum[w] = x;
    __syncthreads();
    if (w == 0) {
        int s = (lane < 16) ? wsum[lane] : 0;
        #pragma unroll
        for (int o = 1; o < 16; o <<= 1) {
            int v = __shfl_up(s, o, 64);
            if (lane >= o) s += v;
        }
        if (lane < 16) wsum[lane] = s;
    }
    __syncthreads();
    int woff = (w > 0) ? wsum[w - 1] : 0;
    if (idx < N_NODES) lp[idx] = x - d + woff;         // exclusive within block
    if (t == 1023) bsum[blockIdx.x] = woff + x;        // block total
}

// ----- scan stage 2: one small block scans the 98 block sums ----------------
__global__ __launch_bounds__(128) void scan2_kernel(const int* __restrict__ bsum,
                                                    int* __restrict__ boff,
                                                    int* __restrict__ rowptr) {
    __shared__ int wt[2];
    const int t = threadIdx.x;
    const int lane = t & 63, w = t >> 6;
    int v = (t < NB) ? bsum[t] : 0;
    int x = v;
    #pragma unroll
    for (int o = 1; o < 64; o <<= 1) {
        int u = __shfl_up(x, o, 64);
        if (lane >= o) x += u;
    }
    if (lane == 63) wt[w] = x;
    __syncthreads();
    int off = (w == 1) ? wt[0] : 0;
    int ex = x - v + off;
    if (t < NB) boff[t] = ex;
    if (t == NB - 1) rowptr[N_NODES] = ex + v;
}

// ---- scan stage 3: add block offsets; write rowptr, cursor, bucket cursors ----
__global__ __launch_bounds__(1024) void scan3_kernel(const int* __restrict__ lp,
                                                     const int* __restrict__ boff,
                                                     int* __restrict__ rowptr,
                                                     int* __restrict__ cursor,
                                                     int* __restrict__ bcur) {
    int idx = blockIdx.x * 1024 + threadIdx.x;
    if (idx >= N_NODES) return;
    int r = lp[idx] + boff[blockIdx.x];
    rowptr[idx] = r;
    cursor[idx] = r;
    if ((idx & 255) == 0) bcur[idx >> 8] = r;          // bucket base = rowptr[b*256]
}

// --- CSR pass A: LDS-aggregated bucket binning (contention-free atomics) ---
__global__ __launch_bounds__(256) void binscatter_kernel(const int* __restrict__ ei,
                                                         int* __restrict__ bcur,
                                                         int2* __restrict__ pairs) {
    __shared__ int cnt[NBUCK];
    __shared__ int bas[NBUCK];
    const int e0 = blockIdx.x * SCHUNK;
    int e1 = e0 + SCHUNK; if (e1 > N_EDGES) e1 = N_EDGES;
    for (int b = threadIdx.x; b < NBUCK; b += 256) cnt[b] = 0;
    __syncthreads();
    // pass 1: local histogram of this chunk's dst buckets
    for (int i = e0 + threadIdx.x; i < e1; i += 256)
        atomicAdd(&cnt[ei[N_EDGES + i] >> 8], 1);
    __syncthreads();
    // reserve one global range per non-empty bucket (~1 atomic hit/counter/block)
    for (int b = threadIdx.x; b < NBUCK; b += 256) {
        int c = cnt[b];
        bas[b] = c ? atomicAdd(&bcur[b], c) : 0;
        cnt[b] = 0;                                   // reuse as local cursor
    }
    __syncthreads();
    // pass 2: place pairs (chunk re-read is L2-hot)
    for (int i = e0 + threadIdx.x; i < e1; i += 256) {
        int s = ei[i];
        int t = ei[N_EDGES + i];
        int b = t >> 8;
        int pos = bas[b] + atomicAdd(&cnt[b], 1);
        pairs[pos] = make_int2(s, t);
    }
}

// --- CSR pass B: finalize within each bucket (L2-resident write window) ----
__global__ __launch_bounds__(256) void finalize_kernel(const int* __restrict__ rowptr,
                                                       const int2* __restrict__ pairs,
                                                       int* __restrict__ cursor,
                                                       int* __restrict__ csr_src) {
    int b = blockIdx.x;
    int n0 = b << 8;
    int n1 = n0 + 256; if (n1 > N_NODES) n1 = N_NODES;
    int rs = rowptr[n0], re = rowptr[n1];
    for (int j = rs + threadIdx.x; j < re; j += 256) {
        int2 p = pairs[j];
        int pos = atomicAdd(&cursor[p.y], 1);
        csr_src[pos] = p.x;
    }
}

// ---- gather layer 1: per-dst wave; fused ELU + GEMM2(64->7) + att2 halves ----
__global__ __launch_bounds__(256) void gather1_kernel(
        const int* __restrict__ rowptr, const int* __restrict__ csr_src,
        const float* __restrict__ als, const float* __restrict__ ald,
        const unsigned short* __restrict__ h1b, const float* __restrict__ b1,
        const float* __restrict__ W2, const float* __restrict__ a2s,
        const float* __restrict__ a2d,
        unsigned short* __restrict__ g2b, float* __restrict__ al2s,
        float* __restrict__ al2d) {
    int wid = (blockIdx.x * 256 + threadIdx.x) >> 6;     // one wave per dst node
    if (wid >= N_NODES) return;
    const int lane = threadIdx.x & 63;
    const int h = lane >> 3;
    const int rs = rowptr[wid], re = rowptr[wid + 1];
    const float aldt = ald[wid * 8 + h];
    // self loop
    float e = als[wid * 8 + h] + aldt;
    e = (e >= 0.f) ? e : 0.2f * e;
    float p = __expf(e);
    float acc = p * bf2f(h1b[(size_t)wid * HD + lane]);
    float z = p;
    // incoming edges, with next-src prefetch
    int j = rs;
    int s_next = (j < re) ? csr_src[j] : 0;
    while (j < re) {
        int s = s_next;
        ++j;
        if (j < re) s_next = csr_src[j];
        float e2 = als[s * 8 + h] + aldt;
        e2 = (e2 >= 0.f) ? e2 : 0.2f * e2;
        float p2 = __expf(e2);
        acc = fmaf(p2, bf2f(h1b[(size_t)s * HD + lane]), acc);
        z += p2;
    }
    // epilogue: alpha-normalize + bias + ELU
    float v = acc / z + b1[lane];
    v = (v > 0.f) ? v : (__expf(v) - 1.f);
    // fused GEMM2: g[c] = sum_j v_j * W2[j][c]  (butterfly over the wave)
    float w[CC];
    #pragma unroll
    for (int c = 0; c < CC; ++c) w[c] = W2[lane * CC + c];
    float g[CC];
    #pragma unroll
    for (int c = 0; c < CC; ++c) {
        float r = v * w[c];
        #pragma unroll
        for (int d = 1; d < 64; d <<= 1) r += __shfl_xor(r, d, 64);
        g[c] = r;
    }
    float s2 = 0.f, d2 = 0.f;
    #pragma unroll
    for (int c = 0; c < CC; ++c) { s2 += g[c] * a2s[c]; d2 += g[c] * a2d[c]; }
    if (lane < CC) g2b[(size_t)wid * 8 + lane] = f2bf(g[lane]);
    if (lane == CC) g2b[(size_t)wid * 8 + CC] = 0;
    if (lane == 8) al2s[wid] = s2;
    if (lane == 9) al2d[wid] = d2;
}

// -------- gather layer 2: 8 lanes per dst node, fused log_softmax ----------
__global__ __launch_bounds__(256) void gather2_kernel(
        const int* __restrict__ rowptr, const int* __restrict__ csr_src,
        const float* __restrict__ al2s, const float* __restrict__ al2d,
        const unsigned short* __restrict__ g2b, const float* __restrict__ b2,
        float* __restrict__ out) {
    int gid = blockIdx.x * 256 + threadIdx.x;
    int n = gid >> 3, c = gid & 7;
    if (n >= N_NODES) return;
    const int rs = rowptr[n], re = rowptr[n + 1];
    const float adn = al2d[n];
    float e = al2s[n] + adn;
    e = (e >= 0.f) ? e : 0.2f * e;
    float p = __expf(e);
    float acc = p * bf2f(g2b[(size_t)n * 8 + c]);
    float z = p;
    int j = rs;
    int s_next = (j < re) ? csr_src[j] : 0;
    while (j < re) {
        int s = s_next;
        ++j;
        if (j < re) s_next = csr_src[j];
        float e2 = al2s[s] + adn;
        e2 = (e2 >= 0.f) ? e2 : 0.2f * e2;
        float p2 = __expf(e2);
        acc = fmaf(p2, bf2f(g2b[(size_t)s * 8 + c]), acc);
        z += p2;
    }
    float o = (c < CC) ? (acc / z + b2[c]) : -1e30f;
    float m = o;
    #pragma unroll
    for (int d = 1; d < 8; d <<= 1) m = fmaxf(m, __shfl_xor(m, d, 8));
    float ex = (c < CC) ? __expf(o - m) : 0.f;
    float sum = ex;
    #pragma unroll
    for (int d = 1; d < 8; d <<= 1) sum += __shfl_xor(sum, d, 8);
    float lse = m + __logf(sum);
    if (c < CC) out[(size_t)n * CC + c] = o - lse;
}

extern "C" void kernel_launch(void* const* d_in, const int* in_sizes, int n_in,
                              void* d_out, int out_size, void* d_ws, size_t ws_size,
                              hipStream_t stream) {
    const float* x   = (const float*)d_in[0];
    const int*   ei  = (const int*)d_in[1];
    const float* W1  = (const float*)d_in[2];
    const float* a1s = (const float*)d_in[3];
    const float* a1d = (const float*)d_in[4];
    const float* b1  = (const float*)d_in[5];
    const float* W2  = (const float*)d_in[6];
    const float* a2s = (const float*)d_in[7];
    const float* a2d = (const float*)d_in[8];
    const float* b2  = (const float*)d_in[9];
    float* out = (float*)d_out;

    // byte-offset workspace allocator (64B aligned)
    char* base = (char*)d_ws;
    size_t off = 0;
    auto alloc = [&](size_t bytes) { char* p = base + off; off = (off + bytes + 63) & ~(size_t)63; return p; };
    unsigned short* h1b = (unsigned short*)alloc((size_t)N_NODES * HD * 2);
    unsigned short* wf  = (unsigned short*)alloc((size_t)NKT * 4 * 64 * 8 * 2);
    float* als  = (float*)alloc((size_t)N_NODES * 8 * 4);
    float* ald  = (float*)alloc((size_t)N_NODES * 8 * 4);
    unsigned short* g2b = (unsigned short*)alloc((size_t)N_NODES * 8 * 2);
    float* al2s = (float*)alloc((size_t)N_NODES * 4);
    float* al2d = (float*)alloc((size_t)N_NODES * 4);
    int* rowptr = (int*)alloc((size_t)(N_NODES + 1) * 4);
    int* cursor = (int*)alloc((size_t)N_NODES * 4);
    int* deg    = (int*)alloc((size_t)N_NODES * 4);
    int* lp     = (int*)alloc((size_t)N_NODES * 4);
    int* bsum   = (int*)alloc((size_t)NB * 4);
    int* boff   = (int*)alloc((size_t)NB * 4);
    int* bcur   = (int*)alloc((size_t)NBUCK * 4);
    int2* pairs = (int2*)alloc((size_t)N_EDGES * 8);
    int* csr_src= (int*)alloc((size_t)N_EDGES * 4);

    hipMemsetAsync(deg, 0, (size_t)N_NODES * sizeof(int), stream);
    w1prep_kernel<<<(NKT * 4 * 64 + 255) / 256, 256, 0, stream>>>(W1, wf);
    hist_kernel<<<(N_EDGES + 255) / 256, 256, 0, stream>>>(ei, deg);
    scan1_kernel<<<NB, 1024, 0, stream>>>(deg, lp, bsum);
    scan2_kernel<<<1, 128, 0, stream>>>(bsum, boff, rowptr);
    scan3_kernel<<<NB, 1024, 0, stream>>>(lp, boff, rowptr, cursor, bcur);
    binscatter_kernel<<<SBLK, 256, 0, stream>>>(ei, bcur, pairs);

    gemm1_kernel<<<(N_NODES + 63) / 64, 256, 0, stream>>>(x, wf, h1b);
    att1_kernel<<<(N_NODES * 8 + 255) / 256, 256, 0, stream>>>(h1b, a1s, a1d, als, ald);

    finalize_kernel<<<NBUCK, 256, 0, stream>>>(rowptr, pairs, cursor, csr_src);

    gather1_kernel<<<(N_NODES * 64 + 255) / 256, 256, 0, stream>>>(
        rowptr, csr_src, als, ald, h1b, b1, W2, a2s, a2d, g2b, al2s, al2d);
    gather2_kernel<<<(N_NODES * 8 + 255) / 256, 256, 0, stream>>>(
        rowptr, csr_src, al2s, al2d, g2b, b2, out);
}